// Round 16
// baseline (698.696 us; speedup 1.0000x reference)
//
#include <hip/hip_runtime.h>
#include <math.h>

#pragma clang fp contract(off)

typedef float v2f __attribute__((ext_vector_type(2)));
typedef float v4f __attribute__((ext_vector_type(4)));

// Exact-FMA helpers: ONLY with multiplier 0.125f (pow2 -> product exact ->
// fma == mul-then-add BIT-IDENTICAL). c15 chains stay mul+add.
__device__ __forceinline__ v2f fma2(v2f q, v2f c, v2f acc) {
    return __builtin_elementwise_fma(q, c, acc);
}
__device__ __forceinline__ v4f fma4(v4f q, v4f c, v4f acc) {
    return __builtin_elementwise_fma(q, c, acc);
}

#define RR 7
#define HH 2048
#define WW 2048
#define PH 2062
#define PW 2062
#define PITCH 2080
#define PLANE (PITCH * PH)

#define BLK 64          // ONE wave per block
#define WVOUT 240       // 60 lanes x 4 px; 64 lanes stage 256 cols (240+16 halo)
#define TYB 8
#define GX 9            // 9*240 = 2160 >= 2062
#define GY 258          // 258*8 = 2064 >= 2062

__global__ __launch_bounds__(256) void sw_pad(const float* __restrict__ img,
                                              float* __restrict__ dst) {
    int idx = blockIdx.x * blockDim.x + threadIdx.x;
    if (idx >= PW * PH) return;
    int y = idx / PW, x = idx - y * PW;
    int sy = y - RR; sy = sy < 0 ? 0 : (sy > HH - 1 ? HH - 1 : sy);
    int sx = x - RR; sx = sx < 0 ? 0 : (sx > WW - 1 ? WW - 1 : sx);
    const float* p = img + ((long)sy * WW + sx) * 3;
    long o = (long)y * PITCH + x;
    dst[o] = p[0];
    dst[(long)PLANE + o] = p[1];
    dst[2L * PLANE + o] = p[2];
}

__global__ __launch_bounds__(256) void sw_crop(const float* __restrict__ src,
                                               float* __restrict__ out) {
    int idx = blockIdx.x * blockDim.x + threadIdx.x;
    if (idx >= HH * WW) return;
    int y = idx / WW, x = idx - y * WW;
    long o = (long)(y + RR) * PITCH + (x + RR);
    out[(long)idx * 3 + 0] = src[o];
    out[(long)idx * 3 + 1] = src[(long)PLANE + o];
    out[(long)idx * 3 + 2] = src[2L * PLANE + o];
}

// Masked quad load: cols gc..gc+3 of row r; zero outside [0,PW) x [0,PH).
// gc is 0 mod 4 -> left-OOB quads are FULLY oob (gc=-8,-4: gc+3<0 -> zeros);
// right edge has exactly one partial quad (gc=2060).
__device__ __forceinline__ v4f load_quad(const float* __restrict__ sp,
                                         int r, int gc) {
    v4f v = {0.0f, 0.0f, 0.0f, 0.0f};
    if (r >= 0 && r < PH) {
        const float* p = sp + (long)r * PITCH + gc;
        if (gc >= 0 && gc <= PW - 4) {
            v = *(const v4f*)p;
        } else if (gc >= 0 && gc < PW) {      // right partial
            v.x = p[0];
            if (gc + 1 < PW) v.y = p[1];
            if (gc + 2 < PW) v.z = p[2];
        }
    }
    return v;
}

// Horizontal xy-chain tap (i = pixel-relative tap 0..14). Chain order/rounding
// identical to the verified R12 kernel: aL i0 init, i1..7 fma; aR i7 init,
// i8..14 fma; f i0 init, i1..14 mul+add; xc at i7.
#define XY_TAP(i, qxy, w, aL, aR, f, xc)                              \
    do {                                                              \
        if ((i) == 0) { aL = 0.125f * (qxy); f = c15 * (qxy); }       \
        else if ((i) <= 14) {                                         \
            if ((i) <= 7) aL = fma2((qxy), c125v, aL);                \
            if ((i) == 7) { aR = 0.125f * (qxy); xc = (w); }          \
            if ((i) > 7)  aR = fma2((qxy), c125v, aR);                \
            f = f + c15 * (qxy);                                      \
        }                                                             \
    } while (0)

// z-chain for a PIXEL PAIR, jj = pair-relative step 0..15 (lane .x = first px
// tap jj, lane .y = second px tap jj-1; .y init via exact add-to-zero at jj=1).
// Identical to verified R12 code.
#define Z_TAP(jj, qz, zL, zR)                                         \
    do {                                                              \
        if ((jj) == 0) { zL = (v2f){0.125f * (qz), 0.0f}; }           \
        else if ((jj) >= 1 && (jj) <= 7) {                            \
            v2f qzz = {(qz), (qz)};                                   \
            zL = fma2(qzz, c125v, zL);                                \
            if ((jj) == 7) zR.x = 0.125f * (qz);                      \
        } else if ((jj) == 8) {                                       \
            float t = 0.125f * (qz);                                  \
            zR.x = zR.x + t; zL.y = zL.y + t; zR.y = t;               \
        } else if ((jj) >= 9 && (jj) <= 14) {                         \
            v2f qzz = {(qz), (qz)};                                   \
            zR = fma2(qzz, c125v, zR);                                \
        } else if ((jj) == 15) {                                      \
            zR.y = fmaf(0.125f, (qz), zR.y);                          \
        }                                                             \
    } while (0)

// argmin over the 8 candidates, candidate ORDER identical to baseline.
#define ARGMIN_PX(aL, aR, f, xc, dzl, dzr, outv)                      \
    do {                                                              \
        v2f xcp = {(xc), (xc)};                                       \
        v2f dL = (aL) - xcp, dR = (aR) - xcp, dF = (f) - xcp;         \
        float d0 = dL.x, d1 = dR.x, d2 = dL.y, d3 = dR.y;             \
        float d4 = dF.x, d5 = dF.y, d6 = (dzl), d7 = (dzr);           \
        float best = d0, ba = fabsf(d0), a;                           \
        a = fabsf(d1); if (a < ba) { ba = a; best = d1; }             \
        a = fabsf(d2); if (a < ba) { ba = a; best = d2; }             \
        a = fabsf(d3); if (a < ba) { ba = a; best = d3; }             \
        a = fabsf(d4); if (a < ba) { ba = a; best = d4; }             \
        a = fabsf(d5); if (a < ba) { ba = a; best = d5; }             \
        a = fabsf(d6); if (a < ba) { ba = a; best = d6; }             \
        a = fabsf(d7); if (a < ba) { ba = a; best = d7; }             \
        outv = (xc) + best;                                           \
    } while (0)

__global__ __launch_bounds__(BLK) void sw_iter(const float* __restrict__ src,
                                               float* __restrict__ dst) {
    // 4 px/lane: halves LDS reads per pixel (R16 lever; DS pipe was ~67% busy).
    // LDS 8 KB: [chunk-row s 0..1][phase col%4][staging-lane 0..63] float4
    // {vL,vR,vF,X}. Reads at stream step j: all lanes hit phase (1+j)&3 at
    // index l+((1+j)>>2) -> contiguous 16B stride, conflict-free.
    __shared__ float4 lds4[2 * 4 * 64];
    const int l = threadIdx.x;
    const int xw0 = blockIdx.x * WVOUT;
    const int y0 = blockIdx.y * TYB;
    const int z = blockIdx.z;
    const float* sp = src + (long)z * PLANE;
    float* dp = dst + (long)z * PLANE;

    const int gc0 = xw0 - 8 + 4 * l;      // staged quad base col (0 mod 4)
    const int oc0 = xw0 + 4 * l;          // output cols oc0..oc0+3
    const bool comp = (l < 60) && (oc0 < PW);

    const float c15 = 1.0f / 15.0f;
    const v2f c125v = {0.125f, 0.125f};
    const v4f c125v4 = {0.125f, 0.125f, 0.125f, 0.125f};

    // register ring: 16 rows x 4 staged cols (slot = (row-y0) & 15)
    v4f xab[16];
#pragma unroll
    for (int i = 0; i < 16; ++i) xab[i] = (v4f){0.0f, 0.0f, 0.0f, 0.0f};

    // warm-up rows y0-7..y0+6 (load_quad guards r<PH: R14 lesson)
#pragma unroll
    for (int k = 0; k < 14; ++k) {
        xab[(k + 9) & 15] = load_quad(sp, y0 - 7 + k, gc0);
    }
    v4f pf[2];
    pf[0] = load_quad(sp, y0 + 7, gc0);
    pf[1] = load_quad(sp, y0 + 8, gc0);

#pragma unroll
    for (int c2 = 0; c2 < TYB / 2; ++c2) {
        // ---- vertical: rows m = y0+2*c2+s, 4 cols per lane ----
#pragma unroll
        for (int s = 0; s < 2; ++s) {
            const int jm = (2 * c2 + s) & 15;
            xab[(jm + 7) & 15] = pf[s];

            v4f aL = 0.125f * xab[(jm + 9) & 15];
#pragma unroll
            for (int k = 1; k < 8; ++k)
                aL = fma4(xab[(jm + 9 + k) & 15], c125v4, aL);
            v4f aR = 0.125f * xab[jm & 15];
#pragma unroll
            for (int k = 8; k < 15; ++k)
                aR = fma4(xab[(jm + 9 + k) & 15], c125v4, aR);
            v4f aF = c15 * xab[(jm + 9) & 15];
#pragma unroll
            for (int k = 1; k < 15; ++k)
                aF = aF + c15 * xab[(jm + 9 + k) & 15];
            const v4f X = xab[jm & 15];

            float4* wb = lds4 + s * 256;            // s*4*64
            wb[0 * 64 + l] = make_float4(aL.x, aR.x, aF.x, X.x);
            wb[1 * 64 + l] = make_float4(aL.y, aR.y, aF.y, X.y);
            wb[2 * 64 + l] = make_float4(aL.z, aR.z, aF.z, X.z);
            wb[3 * 64 + l] = make_float4(aL.w, aR.w, aF.w, X.w);
        }
        asm volatile("s_waitcnt lgkmcnt(0)" ::: "memory");
        __builtin_amdgcn_sched_barrier(0);

        // prefetch next chunk's 2 rows (hidden under horizontal)
        if (c2 + 1 < TYB / 2) {
            pf[0] = load_quad(sp, y0 + 2 * (c2 + 1) + 7, gc0);
            pf[1] = load_quad(sp, y0 + 2 * (c2 + 1) + 8, gc0);
        }

        // ---- horizontal: 4 px/lane, 18-tap stream ----
        if (comp) {
#pragma unroll
            for (int s = 0; s < 2; ++s) {
                const int m = y0 + 2 * c2 + s;
                if (m >= PH) break;
                const float4* rb = lds4 + s * 256;

                v2f aL0, aR0, f0, aL1, aR1, f1;
                v2f aL2, aR2, f2, aL3, aR3, f3;
                v2f zL01, zR01, zL23, zR23;
                float xc0, xc1, xc2, xc3;

                // stream cols oc0-7 .. oc0+10 ascending; px p taps at j=p..p+14
#pragma unroll
                for (int j = 0; j < 18; ++j) {
                    float4 q = rb[((1 + j) & 3) * 64 + l + ((1 + j) >> 2)];
                    v2f qxy = {q.x, q.y};
                    if (j <= 14)           XY_TAP(j,     qxy, q.w, aL0, aR0, f0, xc0);
                    if (j >= 1 && j <= 15) XY_TAP(j - 1, qxy, q.w, aL1, aR1, f1, xc1);
                    if (j >= 2 && j <= 16) XY_TAP(j - 2, qxy, q.w, aL2, aR2, f2, xc2);
                    if (j >= 3)            XY_TAP(j - 3, qxy, q.w, aL3, aR3, f3, xc3);
                    Z_TAP(j, q.z, zL01, zR01);
                    if (j >= 2) Z_TAP(j - 2, q.z, zL23, zR23);
                }

                v2f xcz01 = {xc0, xc1};
                v2f dzL01 = zL01 - xcz01, dzR01 = zR01 - xcz01;
                v2f xcz23 = {xc2, xc3};
                v2f dzL23 = zL23 - xcz23, dzR23 = zR23 - xcz23;

                float o0, o1, o2, o3;
                ARGMIN_PX(aL0, aR0, f0, xc0, dzL01.x, dzR01.x, o0);
                ARGMIN_PX(aL1, aR1, f1, xc1, dzL01.y, dzR01.y, o1);
                ARGMIN_PX(aL2, aR2, f2, xc2, dzL23.x, dzR23.x, o2);
                ARGMIN_PX(aL3, aR3, f3, xc3, dzL23.y, dzR23.y, o3);

                float* op = dp + (long)m * PITCH + oc0;
                if (oc0 + 3 < PW) {
                    *(float4*)op = make_float4(o0, o1, o2, o3);
                } else {                       // right-edge partial store
                    op[0] = o0;
                    if (oc0 + 1 < PW) op[1] = o1;
                    if (oc0 + 2 < PW) op[2] = o2;
                }
            }
        }
    }
}

extern "C" void kernel_launch(void* const* d_in, const int* in_sizes, int n_in,
                              void* d_out, int out_size, void* d_ws, size_t ws_size,
                              hipStream_t stream) {
    (void)in_sizes; (void)n_in; (void)out_size; (void)ws_size;
    const float* img = (const float*)d_in[0];
    float* out = (float*)d_out;
    float* A = (float*)d_ws;
    float* B = A + 3L * PLANE;

    {
        int total = PW * PH;
        int g = (total + 255) / 256;
        sw_pad<<<dim3(g), dim3(256), 0, stream>>>(img, A);
    }
    dim3 grid(GX, GY, 3), block(BLK);
    for (int i = 0; i < 10; ++i) {
        const float* s = (i & 1) ? B : A;
        float* d = (i & 1) ? A : B;
        sw_iter<<<grid, block, 0, stream>>>(s, d);
    }
    // iter 9 (odd) writes A: final state in A.
    {
        int total = HH * WW;
        int g = (total + 255) / 256;
        sw_crop<<<dim3(g), dim3(256), 0, stream>>>(A, out);
    }
}